// Round 4
// baseline (403.197 us; speedup 1.0000x reference)
//
#include <hip/hip_runtime.h>
#include <hip/hip_bf16.h>
#include <cstdint>

typedef __attribute__((ext_vector_type(8))) short bf16x8;
typedef __attribute__((ext_vector_type(4))) short bf16x4;
typedef __attribute__((ext_vector_type(4))) float f32x4;

__device__ __forceinline__ short cvt_bf16(float f) {
  union { float f; uint32_t u; } x; x.f = f;
  uint32_t r = x.u + 0x7FFFu + ((x.u >> 16) & 1u);  // RNE
  return (short)(r >> 16);
}
__device__ __forceinline__ float bf16_to_f(short s) {
  union { uint32_t u; float f; } x; x.u = ((uint32_t)(uint16_t)s) << 16;
  return x.f;
}

// tanh(x) = 1 - 2/(e^{2x}+1); exp2 form never overflows the denominator.
__device__ __forceinline__ float tanh_fast(float x) {
  float e = __builtin_amdgcn_exp2f(x * 2.8853900817779268f);  // 2*log2(e)
  return 1.0f - 2.0f * __builtin_amdgcn_rcpf(e + 1.0f);
}

// async global->LDS, 16 B per lane; lds base must be wave-uniform (lane i lands at base+16*i)
__device__ __forceinline__ void load_lds16(void* lds, const void* g) {
  __builtin_amdgcn_global_load_lds(
      (const __attribute__((address_space(1))) void*)g,
      (__attribute__((address_space(3))) void*)lds, 16, 0, 0);
}

// ---------- f32 -> (hi,lo) bf16 split convert ----------
__global__ __launch_bounds__(256) void k_convert_split(const float* __restrict__ in,
                                                       short* __restrict__ hi,
                                                       short* __restrict__ lo, int n4) {
  int i = blockIdx.x * 256 + threadIdx.x;
  int stride = gridDim.x * 256;
  for (; i < n4; i += stride) {
    float4 v = ((const float4*)in)[i];
    bf16x4 h, l;
    h.x = cvt_bf16(v.x); h.y = cvt_bf16(v.y); h.z = cvt_bf16(v.z); h.w = cvt_bf16(v.w);
    l.x = cvt_bf16(v.x - bf16_to_f(h.x));
    l.y = cvt_bf16(v.y - bf16_to_f(h.y));
    l.z = cvt_bf16(v.z - bf16_to_f(h.z));
    l.w = cvt_bf16(v.w - bf16_to_f(h.w));
    ((bf16x4*)hi)[i] = h;
    ((bf16x4*)lo)[i] = l;
  }
}

// ---------- LDS-tiled transpose + f32->bf16 split: out[c*R+r] = in[r*C+c] ----------
__global__ __launch_bounds__(256) void k_transpose_split(const float* __restrict__ in,
                                                         short* __restrict__ hi,
                                                         short* __restrict__ lo,
                                                         int R, int C) {
  __shared__ float tile[32][33];
  int r0 = blockIdx.x * 32, c0 = blockIdx.y * 32;
  int j = threadIdx.x & 31, i0 = threadIdx.x >> 5;
  #pragma unroll
  for (int i = i0; i < 32; i += 8) {
    int c = c0 + j;
    tile[i][j] = (c < C) ? in[(size_t)(r0 + i) * C + c] : 0.f;
  }
  __syncthreads();
  #pragma unroll
  for (int i = i0; i < 32; i += 8) {
    float v = tile[j][i];
    short h = cvt_bf16(v);
    hi[(size_t)(c0 + i) * R + r0 + j] = h;
    lo[(size_t)(c0 + i) * R + r0 + j] = cvt_bf16(v - bf16_to_f(h));
  }
}

// ---------- plain transpose + cvt (for w4, zero-pad cols >= C) ----------
__global__ __launch_bounds__(256) void k_transpose_cvt(const float* __restrict__ in,
                                                       short* __restrict__ out,
                                                       int R, int C) {
  __shared__ float tile[32][33];
  int r0 = blockIdx.x * 32, c0 = blockIdx.y * 32;
  int j = threadIdx.x & 31, i0 = threadIdx.x >> 5;
  #pragma unroll
  for (int i = i0; i < 32; i += 8) {
    int c = c0 + j;
    tile[i][j] = (c < C) ? in[(size_t)(r0 + i) * C + c] : 0.f;
  }
  __syncthreads();
  #pragma unroll
  for (int i = i0; i < 32; i += 8)
    out[(size_t)(c0 + i) * R + r0 + j] = cvt_bf16(tile[j][i]);
}

// ---------- fb[b][t][a] = text[b,t,:] . w2[:,a] + bias[a]  (K=300, exact f32) ----------
__global__ __launch_bounds__(256) void k_fb(const float* __restrict__ text,
                                            const float* __restrict__ w2,
                                            const float* __restrict__ bias,
                                            float* __restrict__ fb) {
  int b = blockIdx.x, t0 = blockIdx.y * 8, a = threadIdx.x;
  float acc[8] = {0.f,0.f,0.f,0.f,0.f,0.f,0.f,0.f};
  const float* tp = text + ((size_t)b * 40 + t0) * 300;
  for (int k = 0; k < 300; k++) {
    float wv = w2[k * 256 + a];
    #pragma unroll
    for (int j = 0; j < 8; j++) acc[j] += tp[j * 300 + k] * wv;
  }
  float bv = bias[a];
  #pragma unroll
  for (int j = 0; j < 8; j++)
    fb[((size_t)b * 40 + t0 + j) * 256 + a] = acc[j] + bv;
}

// ---------- split-bf16 MFMA GEMM (~f32 precision): C = (Ah+Al) * (Bh+Bl)^T ----------
__global__ __launch_bounds__(256) void k_gemm_split(const short* __restrict__ Ah,
                                                    const short* __restrict__ Al,
                                                    const short* __restrict__ BTh,
                                                    const short* __restrict__ BTl,
                                                    float* __restrict__ C,
                                                    int K, int ldc) {
  __shared__ __align__(16) short Ash[64][72];
  __shared__ __align__(16) short Asl[64][72];
  __shared__ __align__(16) short Bsh[64][72];
  __shared__ __align__(16) short Bsl[64][72];
  int m0 = blockIdx.x * 64, n0 = blockIdx.y * 64;
  int tid = threadIdx.x, lane = tid & 63, wave = tid >> 6;
  int wm = (wave & 1) * 32, wn = (wave >> 1) * 32;
  int srow = tid >> 3, sseg = (tid & 7) * 8;
  f32x4 acc[2][2];
  #pragma unroll
  for (int i = 0; i < 2; i++)
    #pragma unroll
    for (int j = 0; j < 2; j++) acc[i][j] = (f32x4){0.f, 0.f, 0.f, 0.f};
  int mrow = lane & 15, quad = lane >> 4;

  for (int k0 = 0; k0 < K; k0 += 64) {
    size_t aoff0 = (size_t)(m0 + srow) * K + k0 + sseg;
    size_t aoff1 = aoff0 + (size_t)32 * K;
    size_t boff0 = (size_t)(n0 + srow) * K + k0 + sseg;
    size_t boff1 = boff0 + (size_t)32 * K;
    bf16x8 a0h = *(const bf16x8*)(Ah + aoff0);
    bf16x8 a1h = *(const bf16x8*)(Ah + aoff1);
    bf16x8 a0l = *(const bf16x8*)(Al + aoff0);
    bf16x8 a1l = *(const bf16x8*)(Al + aoff1);
    bf16x8 b0h = *(const bf16x8*)(BTh + boff0);
    bf16x8 b1h = *(const bf16x8*)(BTh + boff1);
    bf16x8 b0l = *(const bf16x8*)(BTl + boff0);
    bf16x8 b1l = *(const bf16x8*)(BTl + boff1);
    __syncthreads();
    *(bf16x8*)&Ash[srow][sseg] = a0h;  *(bf16x8*)&Ash[srow + 32][sseg] = a1h;
    *(bf16x8*)&Asl[srow][sseg] = a0l;  *(bf16x8*)&Asl[srow + 32][sseg] = a1l;
    *(bf16x8*)&Bsh[srow][sseg] = b0h;  *(bf16x8*)&Bsh[srow + 32][sseg] = b1h;
    *(bf16x8*)&Bsl[srow][sseg] = b0l;  *(bf16x8*)&Bsl[srow + 32][sseg] = b1l;
    __syncthreads();
    #pragma unroll
    for (int ks = 0; ks < 2; ks++) {
      int kk = ks * 32 + quad * 8;
      bf16x8 ah[2], al[2], bh[2], bl[2];
      ah[0] = *(const bf16x8*)&Ash[wm + mrow][kk];
      ah[1] = *(const bf16x8*)&Ash[wm + 16 + mrow][kk];
      al[0] = *(const bf16x8*)&Asl[wm + mrow][kk];
      al[1] = *(const bf16x8*)&Asl[wm + 16 + mrow][kk];
      bh[0] = *(const bf16x8*)&Bsh[wn + mrow][kk];
      bh[1] = *(const bf16x8*)&Bsh[wn + 16 + mrow][kk];
      bl[0] = *(const bf16x8*)&Bsl[wn + mrow][kk];
      bl[1] = *(const bf16x8*)&Bsl[wn + 16 + mrow][kk];
      #pragma unroll
      for (int i = 0; i < 2; i++)
        #pragma unroll
        for (int j = 0; j < 2; j++) {
          acc[i][j] = __builtin_amdgcn_mfma_f32_16x16x32_bf16(ah[i], bh[j], acc[i][j], 0, 0, 0);
          acc[i][j] = __builtin_amdgcn_mfma_f32_16x16x32_bf16(ah[i], bl[j], acc[i][j], 0, 0, 0);
          acc[i][j] = __builtin_amdgcn_mfma_f32_16x16x32_bf16(al[i], bh[j], acc[i][j], 0, 0, 0);
        }
    }
  }
  int rbase = quad * 4;
  #pragma unroll
  for (int i = 0; i < 2; i++)
    #pragma unroll
    for (int j = 0; j < 2; j++) {
      int col = n0 + wn + j * 16 + mrow;
      #pragma unroll
      for (int r = 0; r < 4; r++) {
        int row = m0 + wm + i * 16 + rbase + r;
        C[(size_t)row * ldc + col] = acc[i][j][r];
      }
    }
}

// ---------- final GEMM, m97-style: 128x64 tile, BK=64, global_load_lds(16B) ----------
// 256 threads = 4 waves; wave w computes rows wm=w*32..+31 (2 m-tiles) x all 64 cols (4 n-tiles).
__global__ __launch_bounds__(256) void k_gemm_f(const short* __restrict__ A,
                                                const short* __restrict__ BT,
                                                const float* __restrict__ bias,
                                                float* __restrict__ C,
                                                int K, int ldc, int nstore) {
  __shared__ __align__(16) short As[128][64];  // 16 KB, unpadded (async-copy layout)
  __shared__ __align__(16) short Bs[64][64];   //  8 KB
  int m0 = blockIdx.x * 128, n0 = blockIdx.y * 64;
  int tid = threadIdx.x, lane = tid & 63, wave = tid >> 6;
  int wm = wave * 32;
  int mrow = lane & 15, quad = lane >> 4;
  int lrow = lane >> 3, lseg = (lane & 7) * 8;  // staging: 8 rows x 8 segs per 1KB chunk

  f32x4 acc[2][4];
  #pragma unroll
  for (int i = 0; i < 2; i++)
    #pragma unroll
    for (int j = 0; j < 4; j++) acc[i][j] = (f32x4){0.f, 0.f, 0.f, 0.f};

  for (int k0 = 0; k0 < K; k0 += 64) {
    __syncthreads();  // previous iteration's fragment reads done
    #pragma unroll
    for (int i = 0; i < 4; i++) {          // A: 16 chunks of 8 rows, 4 per wave
      int c = wave * 4 + i;
      load_lds16(&As[c * 8][0], A + (size_t)(m0 + c * 8 + lrow) * K + k0 + lseg);
    }
    #pragma unroll
    for (int i = 0; i < 2; i++) {          // B: 8 chunks, 2 per wave
      int c = wave * 2 + i;
      load_lds16(&Bs[c * 8][0], BT + (size_t)(n0 + c * 8 + lrow) * K + k0 + lseg);
    }
    __syncthreads();  // drains vmcnt -> LDS tiles ready
    #pragma unroll
    for (int ks = 0; ks < 2; ks++) {
      int kk = ks * 32 + quad * 8;
      bf16x8 af[2], bf[4];
      #pragma unroll
      for (int i = 0; i < 2; i++) af[i] = *(const bf16x8*)&As[wm + i * 16 + mrow][kk];
      #pragma unroll
      for (int j = 0; j < 4; j++) bf[j] = *(const bf16x8*)&Bs[j * 16 + mrow][kk];
      #pragma unroll
      for (int i = 0; i < 2; i++)
        #pragma unroll
        for (int j = 0; j < 4; j++)
          acc[i][j] = __builtin_amdgcn_mfma_f32_16x16x32_bf16(af[i], bf[j], acc[i][j], 0, 0, 0);
    }
  }
  int rbase = quad * 4;
  #pragma unroll
  for (int i = 0; i < 2; i++)
    #pragma unroll
    for (int j = 0; j < 4; j++) {
      int col = n0 + j * 16 + mrow;
      if (col < nstore) {
        float bv = bias[col];
        #pragma unroll
        for (int r = 0; r < 4; r++) {
          int row = m0 + wm + i * 16 + rbase + r;
          C[(size_t)row * ldc + col] = acc[i][j][r] + bv;
        }
      }
    }
}

// ---------- fused middle v4: register logits, batched butterflies, in-reg softmax ----------
// 512 threads = 8 waves = 8 s1-rows; lane owns a-quad (a = 4*lane). LDS: fb slab only (40 KB).
__global__ __launch_bounds__(512, 6) void k_middle(const float* __restrict__ e,
                                                   const float* __restrict__ fb,
                                                   const float* __restrict__ w3,
                                                   const float* __restrict__ bias,
                                                   short* __restrict__ cont) {
  __shared__ __align__(16) float fbs[40 * 256];
  int tid = threadIdx.x, wave = tid >> 6, lane = tid & 63;
  int row0 = blockIdx.x * 8;
  int b = row0 >> 9;          // 512 rows per batch
  int row = row0 + wave;

  const float4* fsrc = (const float4*)(fb + (size_t)b * 40 * 256);
  #pragma unroll
  for (int i = tid; i < 40 * 64; i += 512) ((float4*)fbs)[i] = fsrc[i];
  __syncthreads();

  int a0 = lane * 4;
  float4 e4  = *(const float4*)(e + (size_t)row * 256 + a0);
  float4 w34 = *(const float4*)(w3 + a0);
  float4 bv4 = *(const float4*)(bias + a0);

  // phase 1: per-lane partial logits for all 40 t (no cross-lane ops in the loop)
  float p[40];
  #pragma unroll
  for (int t = 0; t < 40; t++) {
    float4 f4 = *(const float4*)&fbs[t * 256 + a0];
    p[t] = tanh_fast(e4.x + f4.x) * w34.x
         + tanh_fast(e4.y + f4.y) * w34.y
         + tanh_fast(e4.z + f4.z) * w34.z
         + tanh_fast(e4.w + f4.w) * w34.w;
  }
  // batched butterfly: 40 independent 6-step chains (ILP hides bpermute latency)
  #pragma unroll
  for (int s = 32; s >= 1; s >>= 1) {
    #pragma unroll
    for (int t = 0; t < 40; t++) p[t] += __shfl_xor(p[t], s, 64);
  }
  // phase 2: softmax entirely in registers (every lane has all 40 logits)
  float mx = p[0];
  #pragma unroll
  for (int t = 1; t < 40; t++) mx = fmaxf(mx, p[t]);
  float ssum = 0.f;
  #pragma unroll
  for (int t = 0; t < 40; t++) {
    p[t] = __builtin_amdgcn_exp2f((p[t] - mx) * 1.4426950408889634f);
    ssum += p[t];
  }
  float rinv = __builtin_amdgcn_rcpf(ssum);

  // phase 3: text_attn chunk = (sum_t p[t]*fbs[t][chunk])*rinv - bias
  float tax = 0.f, tay = 0.f, taz = 0.f, taw = 0.f;
  #pragma unroll
  for (int t = 0; t < 40; t++) {
    float4 f4 = *(const float4*)&fbs[t * 256 + a0];
    tax += p[t] * f4.x; tay += p[t] * f4.y; taz += p[t] * f4.z; taw += p[t] * f4.w;
  }
  tax = tax * rinv - bv4.x; tay = tay * rinv - bv4.y;
  taz = taz * rinv - bv4.z; taw = taw * rinv - bv4.w;

  short* crow = cont + (size_t)row * 1024 + a0;
  auto st4 = [&](int off, float x, float y, float z, float w) {
    uint32_t lo = (uint32_t)(uint16_t)cvt_bf16(x) | ((uint32_t)(uint16_t)cvt_bf16(y) << 16);
    uint32_t hi = (uint32_t)(uint16_t)cvt_bf16(z) | ((uint32_t)(uint16_t)cvt_bf16(w) << 16);
    uint2 pk; pk.x = lo; pk.y = hi;
    *(uint2*)(crow + off) = pk;
  };
  st4(0,   tanh_fast(e4.x), tanh_fast(e4.y), tanh_fast(e4.z), tanh_fast(e4.w));
  st4(256, tanh_fast(tax),  tanh_fast(tay),  tanh_fast(taz),  tanh_fast(taw));
  st4(512, tanh_fast(e4.x * tax), tanh_fast(e4.y * tay),
           tanh_fast(e4.z * taz), tanh_fast(e4.w * taw));
  st4(768, tanh_fast(e4.x - tax), tanh_fast(e4.y - tay),
           tanh_fast(e4.z - taz), tanh_fast(e4.w - taw));
}

extern "C" void kernel_launch(void* const* d_in, const int* in_sizes, int n_in,
                              void* d_out, int out_size, void* d_ws, size_t ws_size,
                              hipStream_t stream) {
  const float* video = (const float*)d_in[0];  // 16x512x1024
  const float* text  = (const float*)d_in[1];  // 16x40x300
  const float* w1    = (const float*)d_in[2];  // 1024x256
  const float* w2    = (const float*)d_in[3];  // 300x256
  const float* w3    = (const float*)d_in[4];  // 256
  const float* bias  = (const float*)d_in[5];  // 256
  const float* w4    = (const float*)d_in[6];  // 1024x500
  const float* b4    = (const float*)d_in[7];  // 500
  float* out = (float*)d_out;                  // 16x512x500
  char* ws = (char*)d_ws;

  // workspace layout (bytes)
  short* video_hi = (short*)(ws);              // 8192x1024 bf16 = 16,777,216
  short* video_lo = (short*)(ws + 16777216);   // 8192x1024 bf16 = 16,777,216 (aliased w/ contbuf)
  short* contbuf  = (short*)(ws + 16777216);   // dead until after e-GEMM consumes video_lo
  short* w1T_hi   = (short*)(ws + 33554432);   // 256x1024 bf16 = 524,288
  short* w1T_lo   = (short*)(ws + 34078720);   // 256x1024 bf16 = 524,288
  short* w4T      = (short*)(ws + 34603008);   // 512x1024 bf16 = 1,048,576 (rows 500..511 zero)
  float* fbuf     = (float*)(ws + 35651584);   // 16x40x256 f32 = 655,360 (f + bias)
  float* ebuf     = (float*)(ws + 36306944);   // 8192x256 f32  = 8,388,608

  k_convert_split<<<2048, 256, 0, stream>>>(video, video_hi, video_lo, 8388608 / 4);
  k_transpose_split<<<dim3(32, 8), 256, 0, stream>>>(w1, w1T_hi, w1T_lo, 1024, 256);
  k_transpose_cvt<<<dim3(32, 16), 256, 0, stream>>>(w4, w4T, 1024, 500);
  k_fb<<<dim3(16, 5), 256, 0, stream>>>(text, w2, bias, fbuf);
  k_gemm_split<<<dim3(128, 4), 256, 0, stream>>>(video_hi, video_lo, w1T_hi, w1T_lo,
                                                 ebuf, 1024, 256);
  k_middle<<<1024, 512, 0, stream>>>(ebuf, fbuf, w3, bias, contbuf);
  k_gemm_f<<<dim3(64, 8), 256, 0, stream>>>(contbuf, w4T, b4, out, 1024, 500, 500);
}

// Round 5
// 214.559 us; speedup vs baseline: 1.8792x; 1.8792x over previous
//
#include <hip/hip_runtime.h>
#include <hip/hip_bf16.h>
#include <cstdint>

typedef __attribute__((ext_vector_type(8))) short bf16x8;
typedef __attribute__((ext_vector_type(4))) short bf16x4;
typedef __attribute__((ext_vector_type(4))) float f32x4;

__device__ __forceinline__ short cvt_bf16(float f) {
  union { float f; uint32_t u; } x; x.f = f;
  uint32_t r = x.u + 0x7FFFu + ((x.u >> 16) & 1u);  // RNE
  return (short)(r >> 16);
}
__device__ __forceinline__ float bf16_to_f(short s) {
  union { uint32_t u; float f; } x; x.u = ((uint32_t)(uint16_t)s) << 16;
  return x.f;
}

// tanh(x) = 1 - 2/(e^{2x}+1); exp2 form never overflows the denominator.
__device__ __forceinline__ float tanh_fast(float x) {
  float e = __builtin_amdgcn_exp2f(x * 2.8853900817779268f);  // 2*log2(e)
  return 1.0f - 2.0f * __builtin_amdgcn_rcpf(e + 1.0f);
}

// async global->LDS, 16 B per lane; lds base must be wave-uniform (lane i lands at base+16*i)
__device__ __forceinline__ void load_lds16(void* lds, const void* g) {
  __builtin_amdgcn_global_load_lds(
      (const __attribute__((address_space(1))) void*)g,
      (__attribute__((address_space(3))) void*)lds, 16, 0, 0);
}

// ---------- f32 -> (hi,lo) bf16 split convert ----------
__global__ __launch_bounds__(256) void k_convert_split(const float* __restrict__ in,
                                                       short* __restrict__ hi,
                                                       short* __restrict__ lo, int n4) {
  int i = blockIdx.x * 256 + threadIdx.x;
  int stride = gridDim.x * 256;
  for (; i < n4; i += stride) {
    float4 v = ((const float4*)in)[i];
    bf16x4 h, l;
    h.x = cvt_bf16(v.x); h.y = cvt_bf16(v.y); h.z = cvt_bf16(v.z); h.w = cvt_bf16(v.w);
    l.x = cvt_bf16(v.x - bf16_to_f(h.x));
    l.y = cvt_bf16(v.y - bf16_to_f(h.y));
    l.z = cvt_bf16(v.z - bf16_to_f(h.z));
    l.w = cvt_bf16(v.w - bf16_to_f(h.w));
    ((bf16x4*)hi)[i] = h;
    ((bf16x4*)lo)[i] = l;
  }
}

// ---------- LDS-tiled transpose + f32->bf16 split: out[c*R+r] = in[r*C+c] ----------
__global__ __launch_bounds__(256) void k_transpose_split(const float* __restrict__ in,
                                                         short* __restrict__ hi,
                                                         short* __restrict__ lo,
                                                         int R, int C) {
  __shared__ float tile[32][33];
  int r0 = blockIdx.x * 32, c0 = blockIdx.y * 32;
  int j = threadIdx.x & 31, i0 = threadIdx.x >> 5;
  #pragma unroll
  for (int i = i0; i < 32; i += 8) {
    int c = c0 + j;
    tile[i][j] = (c < C) ? in[(size_t)(r0 + i) * C + c] : 0.f;
  }
  __syncthreads();
  #pragma unroll
  for (int i = i0; i < 32; i += 8) {
    float v = tile[j][i];
    short h = cvt_bf16(v);
    hi[(size_t)(c0 + i) * R + r0 + j] = h;
    lo[(size_t)(c0 + i) * R + r0 + j] = cvt_bf16(v - bf16_to_f(h));
  }
}

// ---------- plain transpose + cvt (for w4, zero-pad cols >= C) ----------
__global__ __launch_bounds__(256) void k_transpose_cvt(const float* __restrict__ in,
                                                       short* __restrict__ out,
                                                       int R, int C) {
  __shared__ float tile[32][33];
  int r0 = blockIdx.x * 32, c0 = blockIdx.y * 32;
  int j = threadIdx.x & 31, i0 = threadIdx.x >> 5;
  #pragma unroll
  for (int i = i0; i < 32; i += 8) {
    int c = c0 + j;
    tile[i][j] = (c < C) ? in[(size_t)(r0 + i) * C + c] : 0.f;
  }
  __syncthreads();
  #pragma unroll
  for (int i = i0; i < 32; i += 8)
    out[(size_t)(c0 + i) * R + r0 + j] = cvt_bf16(tile[j][i]);
}

// ---------- fb[b][t][a] = text[b,t,:] . w2[:,a] + bias[a]  (K=300, exact f32) ----------
__global__ __launch_bounds__(256) void k_fb(const float* __restrict__ text,
                                            const float* __restrict__ w2,
                                            const float* __restrict__ bias,
                                            float* __restrict__ fb) {
  int b = blockIdx.x, t0 = blockIdx.y * 8, a = threadIdx.x;
  float acc[8] = {0.f,0.f,0.f,0.f,0.f,0.f,0.f,0.f};
  const float* tp = text + ((size_t)b * 40 + t0) * 300;
  for (int k = 0; k < 300; k++) {
    float wv = w2[k * 256 + a];
    #pragma unroll
    for (int j = 0; j < 8; j++) acc[j] += tp[j * 300 + k] * wv;
  }
  float bv = bias[a];
  #pragma unroll
  for (int j = 0; j < 8; j++)
    fb[((size_t)b * 40 + t0 + j) * 256 + a] = acc[j] + bv;
}

// ---------- split-bf16 MFMA GEMM (~f32 precision): C = (Ah+Al) * (Bh+Bl)^T ----------
__global__ __launch_bounds__(256) void k_gemm_split(const short* __restrict__ Ah,
                                                    const short* __restrict__ Al,
                                                    const short* __restrict__ BTh,
                                                    const short* __restrict__ BTl,
                                                    float* __restrict__ C,
                                                    int K, int ldc) {
  __shared__ __align__(16) short Ash[64][72];
  __shared__ __align__(16) short Asl[64][72];
  __shared__ __align__(16) short Bsh[64][72];
  __shared__ __align__(16) short Bsl[64][72];
  int m0 = blockIdx.x * 64, n0 = blockIdx.y * 64;
  int tid = threadIdx.x, lane = tid & 63, wave = tid >> 6;
  int wm = (wave & 1) * 32, wn = (wave >> 1) * 32;
  int srow = tid >> 3, sseg = (tid & 7) * 8;
  f32x4 acc[2][2];
  #pragma unroll
  for (int i = 0; i < 2; i++)
    #pragma unroll
    for (int j = 0; j < 2; j++) acc[i][j] = (f32x4){0.f, 0.f, 0.f, 0.f};
  int mrow = lane & 15, quad = lane >> 4;

  for (int k0 = 0; k0 < K; k0 += 64) {
    size_t aoff0 = (size_t)(m0 + srow) * K + k0 + sseg;
    size_t aoff1 = aoff0 + (size_t)32 * K;
    size_t boff0 = (size_t)(n0 + srow) * K + k0 + sseg;
    size_t boff1 = boff0 + (size_t)32 * K;
    bf16x8 a0h = *(const bf16x8*)(Ah + aoff0);
    bf16x8 a1h = *(const bf16x8*)(Ah + aoff1);
    bf16x8 a0l = *(const bf16x8*)(Al + aoff0);
    bf16x8 a1l = *(const bf16x8*)(Al + aoff1);
    bf16x8 b0h = *(const bf16x8*)(BTh + boff0);
    bf16x8 b1h = *(const bf16x8*)(BTh + boff1);
    bf16x8 b0l = *(const bf16x8*)(BTl + boff0);
    bf16x8 b1l = *(const bf16x8*)(BTl + boff1);
    __syncthreads();
    *(bf16x8*)&Ash[srow][sseg] = a0h;  *(bf16x8*)&Ash[srow + 32][sseg] = a1h;
    *(bf16x8*)&Asl[srow][sseg] = a0l;  *(bf16x8*)&Asl[srow + 32][sseg] = a1l;
    *(bf16x8*)&Bsh[srow][sseg] = b0h;  *(bf16x8*)&Bsh[srow + 32][sseg] = b1h;
    *(bf16x8*)&Bsl[srow][sseg] = b0l;  *(bf16x8*)&Bsl[srow + 32][sseg] = b1l;
    __syncthreads();
    #pragma unroll
    for (int ks = 0; ks < 2; ks++) {
      int kk = ks * 32 + quad * 8;
      bf16x8 ah[2], al[2], bh[2], bl[2];
      ah[0] = *(const bf16x8*)&Ash[wm + mrow][kk];
      ah[1] = *(const bf16x8*)&Ash[wm + 16 + mrow][kk];
      al[0] = *(const bf16x8*)&Asl[wm + mrow][kk];
      al[1] = *(const bf16x8*)&Asl[wm + 16 + mrow][kk];
      bh[0] = *(const bf16x8*)&Bsh[wn + mrow][kk];
      bh[1] = *(const bf16x8*)&Bsh[wn + 16 + mrow][kk];
      bl[0] = *(const bf16x8*)&Bsl[wn + mrow][kk];
      bl[1] = *(const bf16x8*)&Bsl[wn + 16 + mrow][kk];
      #pragma unroll
      for (int i = 0; i < 2; i++)
        #pragma unroll
        for (int j = 0; j < 2; j++) {
          acc[i][j] = __builtin_amdgcn_mfma_f32_16x16x32_bf16(ah[i], bh[j], acc[i][j], 0, 0, 0);
          acc[i][j] = __builtin_amdgcn_mfma_f32_16x16x32_bf16(ah[i], bl[j], acc[i][j], 0, 0, 0);
          acc[i][j] = __builtin_amdgcn_mfma_f32_16x16x32_bf16(al[i], bh[j], acc[i][j], 0, 0, 0);
        }
    }
  }
  int rbase = quad * 4;
  #pragma unroll
  for (int i = 0; i < 2; i++)
    #pragma unroll
    for (int j = 0; j < 2; j++) {
      int col = n0 + wn + j * 16 + mrow;
      #pragma unroll
      for (int r = 0; r < 4; r++) {
        int row = m0 + wm + i * 16 + rbase + r;
        C[(size_t)row * ldc + col] = acc[i][j][r];
      }
    }
}

// ---------- final GEMM, m97-style: 128x64 tile, BK=64, global_load_lds(16B) ----------
__global__ __launch_bounds__(256) void k_gemm_f(const short* __restrict__ A,
                                                const short* __restrict__ BT,
                                                const float* __restrict__ bias,
                                                float* __restrict__ C,
                                                int K, int ldc, int nstore) {
  __shared__ __align__(16) short As[128][64];  // 16 KB, unpadded (async-copy layout)
  __shared__ __align__(16) short Bs[64][64];   //  8 KB
  int m0 = blockIdx.x * 128, n0 = blockIdx.y * 64;
  int tid = threadIdx.x, lane = tid & 63, wave = tid >> 6;
  int wm = wave * 32;
  int mrow = lane & 15, quad = lane >> 4;
  int lrow = lane >> 3, lseg = (lane & 7) * 8;

  f32x4 acc[2][4];
  #pragma unroll
  for (int i = 0; i < 2; i++)
    #pragma unroll
    for (int j = 0; j < 4; j++) acc[i][j] = (f32x4){0.f, 0.f, 0.f, 0.f};

  for (int k0 = 0; k0 < K; k0 += 64) {
    __syncthreads();
    #pragma unroll
    for (int i = 0; i < 4; i++) {
      int c = wave * 4 + i;
      load_lds16(&As[c * 8][0], A + (size_t)(m0 + c * 8 + lrow) * K + k0 + lseg);
    }
    #pragma unroll
    for (int i = 0; i < 2; i++) {
      int c = wave * 2 + i;
      load_lds16(&Bs[c * 8][0], BT + (size_t)(n0 + c * 8 + lrow) * K + k0 + lseg);
    }
    __syncthreads();
    #pragma unroll
    for (int ks = 0; ks < 2; ks++) {
      int kk = ks * 32 + quad * 8;
      bf16x8 af[2], bf[4];
      #pragma unroll
      for (int i = 0; i < 2; i++) af[i] = *(const bf16x8*)&As[wm + i * 16 + mrow][kk];
      #pragma unroll
      for (int j = 0; j < 4; j++) bf[j] = *(const bf16x8*)&Bs[j * 16 + mrow][kk];
      #pragma unroll
      for (int i = 0; i < 2; i++)
        #pragma unroll
        for (int j = 0; j < 4; j++)
          acc[i][j] = __builtin_amdgcn_mfma_f32_16x16x32_bf16(af[i], bf[j], acc[i][j], 0, 0, 0);
    }
  }
  int rbase = quad * 4;
  #pragma unroll
  for (int i = 0; i < 2; i++)
    #pragma unroll
    for (int j = 0; j < 4; j++) {
      int col = n0 + j * 16 + mrow;
      if (col < nstore) {
        float bv = bias[col];
        #pragma unroll
        for (int r = 0; r < 4; r++) {
          int row = m0 + wm + i * 16 + rbase + r;
          C[(size_t)row * ldc + col] = acc[i][j][r] + bv;
        }
      }
    }
}

// ---------- fused middle v5: 2 rows/wave, chunked butterflies (no big reg array) ----------
// 512 threads = 8 waves; wave w handles rows row0+w and row0+w+8 (16 rows/block).
// Each fbs float4 read feeds both rows (halves LDS traffic vs 1 row/wave).
// Chunk of 4 t x 2 rows = 8 independent 6-step butterfly chains (ILP), only 8 live p-regs.
// NOTE: no min-waves launch bound — round 4's (512,6) cap caused catastrophic spills.
__global__ __launch_bounds__(512) void k_middle(const float* __restrict__ e,
                                                const float* __restrict__ fb,
                                                const float* __restrict__ w3,
                                                const float* __restrict__ bias,
                                                short* __restrict__ cont) {
  __shared__ __align__(16) float fbs[40 * 256];  // 40 KB
  __shared__ float lg[16][40];
  __shared__ float attn[16][40];
  int tid = threadIdx.x, wave = tid >> 6, lane = tid & 63;
  int row0 = blockIdx.x * 16;
  int b = row0 >> 9;          // 512 rows per batch; 16 | 512 so block is batch-pure
  int rowA = row0 + wave, rowB = rowA + 8;

  const float4* fsrc = (const float4*)(fb + (size_t)b * 40 * 256);
  for (int i = tid; i < 40 * 64; i += 512) ((float4*)fbs)[i] = fsrc[i];
  __syncthreads();

  int a0 = lane * 4;
  float4 eA  = *(const float4*)(e + (size_t)rowA * 256 + a0);
  float4 eB  = *(const float4*)(e + (size_t)rowB * 256 + a0);
  float4 w34 = *(const float4*)(w3 + a0);
  float4 bv4 = *(const float4*)(bias + a0);

  // phase 1: logits in chunks of 4 t, both rows; 8 independent butterfly chains
  for (int tc = 0; tc < 40; tc += 4) {
    float pa[4], pb[4];
    #pragma unroll
    for (int u = 0; u < 4; u++) {
      float4 f4 = *(const float4*)&fbs[(tc + u) * 256 + a0];
      pa[u] = tanh_fast(eA.x + f4.x) * w34.x + tanh_fast(eA.y + f4.y) * w34.y
            + tanh_fast(eA.z + f4.z) * w34.z + tanh_fast(eA.w + f4.w) * w34.w;
      pb[u] = tanh_fast(eB.x + f4.x) * w34.x + tanh_fast(eB.y + f4.y) * w34.y
            + tanh_fast(eB.z + f4.z) * w34.z + tanh_fast(eB.w + f4.w) * w34.w;
    }
    #pragma unroll
    for (int s = 32; s >= 1; s >>= 1) {
      #pragma unroll
      for (int u = 0; u < 4; u++) {
        pa[u] += __shfl_xor(pa[u], s, 64);
        pb[u] += __shfl_xor(pb[u], s, 64);
      }
    }
    if (lane == 0) {
      #pragma unroll
      for (int u = 0; u < 4; u++) { lg[wave][tc + u] = pa[u]; lg[wave + 8][tc + u] = pb[u]; }
    }
  }

  // phase 2: wave-local softmax per row (lanes >= 40 idle via -inf/0)
  auto softmax_row = [&](int r) {
    float x = (lane < 40) ? lg[r][lane] : -3.0e38f;
    float m = x;
    #pragma unroll
    for (int s = 32; s >= 1; s >>= 1) m = fmaxf(m, __shfl_xor(m, s, 64));
    float ex = (lane < 40) ? __builtin_amdgcn_exp2f((x - m) * 1.4426950408889634f) : 0.f;
    float ssum = ex;
    #pragma unroll
    for (int s = 32; s >= 1; s >>= 1) ssum += __shfl_xor(ssum, s, 64);
    if (lane < 40) attn[r][lane] = ex * __builtin_amdgcn_rcpf(ssum);
  };
  softmax_row(wave);
  softmax_row(wave + 8);

  // phase 3: text_attn = sum_t attn[t]*fbs[t][chunk] - bias   (sum attn = 1)
  float ax = 0.f, ay = 0.f, az = 0.f, aw = 0.f;
  float bx = 0.f, by = 0.f, bz = 0.f, bw = 0.f;
  for (int t = 0; t < 40; t++) {
    float wa = attn[wave][t], wb = attn[wave + 8][t];  // wave-uniform broadcasts
    float4 f4 = *(const float4*)&fbs[t * 256 + a0];
    ax += wa * f4.x; ay += wa * f4.y; az += wa * f4.z; aw += wa * f4.w;
    bx += wb * f4.x; by += wb * f4.y; bz += wb * f4.z; bw += wb * f4.w;
  }
  ax -= bv4.x; ay -= bv4.y; az -= bv4.z; aw -= bv4.w;
  bx -= bv4.x; by -= bv4.y; bz -= bv4.z; bw -= bv4.w;

  auto emit = [&](int row, float4 e4, float tx, float ty, float tz, float tw) {
    short* crow = cont + (size_t)row * 1024 + a0;
    auto st4 = [&](int off, float x, float y, float z, float w) {
      uint32_t lo = (uint32_t)(uint16_t)cvt_bf16(x) | ((uint32_t)(uint16_t)cvt_bf16(y) << 16);
      uint32_t hi = (uint32_t)(uint16_t)cvt_bf16(z) | ((uint32_t)(uint16_t)cvt_bf16(w) << 16);
      uint2 pk; pk.x = lo; pk.y = hi;
      *(uint2*)(crow + off) = pk;
    };
    st4(0,   tanh_fast(e4.x), tanh_fast(e4.y), tanh_fast(e4.z), tanh_fast(e4.w));
    st4(256, tanh_fast(tx),   tanh_fast(ty),   tanh_fast(tz),   tanh_fast(tw));
    st4(512, tanh_fast(e4.x * tx), tanh_fast(e4.y * ty),
             tanh_fast(e4.z * tz), tanh_fast(e4.w * tw));
    st4(768, tanh_fast(e4.x - tx), tanh_fast(e4.y - ty),
             tanh_fast(e4.z - tz), tanh_fast(e4.w - tw));
  };
  emit(rowA, eA, ax, ay, az, aw);
  emit(rowB, eB, bx, by, bz, bw);
}

extern "C" void kernel_launch(void* const* d_in, const int* in_sizes, int n_in,
                              void* d_out, int out_size, void* d_ws, size_t ws_size,
                              hipStream_t stream) {
  const float* video = (const float*)d_in[0];  // 16x512x1024
  const float* text  = (const float*)d_in[1];  // 16x40x300
  const float* w1    = (const float*)d_in[2];  // 1024x256
  const float* w2    = (const float*)d_in[3];  // 300x256
  const float* w3    = (const float*)d_in[4];  // 256
  const float* bias  = (const float*)d_in[5];  // 256
  const float* w4    = (const float*)d_in[6];  // 1024x500
  const float* b4    = (const float*)d_in[7];  // 500
  float* out = (float*)d_out;                  // 16x512x500
  char* ws = (char*)d_ws;

  // workspace layout (bytes)
  short* video_hi = (short*)(ws);              // 8192x1024 bf16 = 16,777,216
  short* video_lo = (short*)(ws + 16777216);   // 8192x1024 bf16 = 16,777,216 (aliased w/ contbuf)
  short* contbuf  = (short*)(ws + 16777216);   // dead until after e-GEMM consumes video_lo
  short* w1T_hi   = (short*)(ws + 33554432);   // 256x1024 bf16 = 524,288
  short* w1T_lo   = (short*)(ws + 34078720);   // 256x1024 bf16 = 524,288
  short* w4T      = (short*)(ws + 34603008);   // 512x1024 bf16 = 1,048,576 (rows 500..511 zero)
  float* fbuf     = (float*)(ws + 35651584);   // 16x40x256 f32 = 655,360 (f + bias)
  float* ebuf     = (float*)(ws + 36306944);   // 8192x256 f32  = 8,388,608

  k_convert_split<<<2048, 256, 0, stream>>>(video, video_hi, video_lo, 8388608 / 4);
  k_transpose_split<<<dim3(32, 8), 256, 0, stream>>>(w1, w1T_hi, w1T_lo, 1024, 256);
  k_transpose_cvt<<<dim3(32, 16), 256, 0, stream>>>(w4, w4T, 1024, 500);
  k_fb<<<dim3(16, 5), 256, 0, stream>>>(text, w2, bias, fbuf);
  k_gemm_split<<<dim3(128, 4), 256, 0, stream>>>(video_hi, video_lo, w1T_hi, w1T_lo,
                                                 ebuf, 1024, 256);
  k_middle<<<512, 512, 0, stream>>>(ebuf, fbuf, w3, bias, contbuf);
  k_gemm_f<<<dim3(64, 8), 256, 0, stream>>>(contbuf, w4T, b4, out, 1024, 500, 500);
}